// Round 2
// baseline (397.790 us; speedup 1.0000x reference)
//
#include <hip/hip_runtime.h>
#include <cstdint>

typedef __attribute__((ext_vector_type(8))) short short8;
typedef __attribute__((ext_vector_type(4))) float f32x4;

#define NB 16
#define NT 2048
#define ND 1024
#define NC 512
#define NM (NB*NT)   // 32768 rows

#define BM 64        // rows per block
#define BKS 64       // K per pipeline stage (double-buffered)
#define NSTAGE (ND/BKS)  // 16
#define NWAVE 8      // 512 threads

__device__ __forceinline__ unsigned short f2bf(float f){
  unsigned int u = __float_as_uint(f);
  u += 0x7fffu + ((u >> 16) & 1u);   // RNE; inputs are finite normals
  return (unsigned short)(u >> 16);
}

// async 16B global -> LDS DMA (wave-uniform LDS base + lane*16)
__device__ __forceinline__ void async_copy16(const void* g, void* l) {
  __builtin_amdgcn_global_load_lds(
      (const __attribute__((address_space(1))) void*)g,
      (__attribute__((address_space(3))) void*)l,
      16, 0, 0);
}

// ---------------- CAM GEMM + fused softmax ----------------
// Block: 512 threads (8 waves). Tile: 64 rows x full C=512 (softmax in-block).
// Wave w: cols [w*64, w*64+64): ni=4, mi=4, K-stage BKS=64 (two 32-halves).
//
// COUNTED-VMCNT PIPELINE (T4): BKS=64 double-buffer (LDS 148 KiB -> 1
// block/CU, 512 blocks = 2 staggered rounds so epilogue writes overlap the
// next round's K-loop). Each wave issues a UNIFORM 9 DMAs per stage
// (8 B-segs + 1 A-seg), so `s_waitcnt vmcnt(9)` == "previous tile's loads
// complete, current prefetch stays in flight". vmcnt never drains to 0 in
// the main loop; barriers are raw s_barrier (no implicit drain).
//
// LDS layout per buffer (row stride 64 B), 16-B k-chunk XOR-swizzled by row
// (chunk c of row r holds global chunk c ^ (r&3)); swizzle applied on BOTH
// sides: pre-swizzled global source for the DMA (dest stays linear, as
// global_load_lds requires) + swizzled ds_read address.
//   As elem = half*2048 + row*32 + k   (8 KB)
//   Bs elem = half*16384 + col*32 + k  (64 KB)
template<bool PRECONV>
__global__ __launch_bounds__(512, 2) void cam_softmax_kernel(
    const unsigned short* __restrict__ Fb,   // bf16 [32768,1024] (PRECONV)
    const float* __restrict__ F,             // fp32 [32768,1024] (!PRECONV)
    const unsigned short* __restrict__ Wb,   // bf16 [512,1024]
    float* __restrict__ out_soft,
    float* __restrict__ out_raw)
{
  __shared__ alignas(16) unsigned short As[2][BM * BKS];    // 2 x 8 KB
  __shared__ alignas(16) unsigned short Bs[2][NC * BKS];    // 2 x 64 KB
  __shared__ float redmax[NWAVE][BM];
  __shared__ float redsum[NWAVE][BM];

  const int tid    = threadIdx.x;
  const int wave   = tid >> 6;
  const int lane   = tid & 63;
  const int lane15 = lane & 15;
  const int quad   = lane >> 4;
  const int m0     = blockIdx.x * BM;

  // staging geometry (per-lane, loop-invariant)
  const int rr   = lane >> 2;                        // row/col within 16-seg
  const int koff = ((lane & 3) ^ (rr & 3)) * 8;      // pre-swizzled k-chunk
  // fragment-read swizzled k-chunk (elems): c' = quad ^ (row&3)
  const int qsw  = (quad ^ (lane15 & 3)) * 8;

  f32x4 acc[4][4];
  #pragma unroll
  for (int mi = 0; mi < 4; mi++)
    #pragma unroll
    for (int ni = 0; ni < 4; ni++)
      acc[mi][ni] = (f32x4){0.f, 0.f, 0.f, 0.f};

  // ---- staging: 9 uniform DMAs per wave per stage ----
  auto stage = [&](int tile, unsigned short* Asb, unsigned short* Bsb) {
    const int k0 = tile * BKS;
    {   // A: seg s = wave (8 segs of 1 KB)
      const int row  = ((wave & 3) << 4) + rr;
      const int half = wave >> 2;
      async_copy16(Fb + (size_t)(m0 + row) * ND + k0 + half * 32 + koff,
                   Asb + wave * 512);
    }
    #pragma unroll
    for (int t = 0; t < 8; t++) {   // B: segs s2 = wave*8+t (64 segs of 1 KB)
      const int s2   = (wave << 3) + t;
      const int col  = ((s2 & 31) << 4) + rr;
      const int half = s2 >> 5;
      async_copy16(Wb + (size_t)col * ND + k0 + half * 32 + koff,
                   Bsb + s2 * 512);
    }
  };

  auto compute = [&](const unsigned short* Asb, const unsigned short* Bsb) {
    #pragma unroll
    for (int half = 0; half < 2; half++) {
      short8 af[4];
      #pragma unroll
      for (int mi = 0; mi < 4; mi++)
        af[mi] = *reinterpret_cast<const short8*>(
            &Asb[half * 2048 + (mi * 16 + lane15) * 32 + qsw]);
      #pragma unroll
      for (int ni = 0; ni < 4; ni++) {
        const short8 bf = *reinterpret_cast<const short8*>(
            &Bsb[half * 16384 + (wave * 64 + ni * 16 + lane15) * 32 + qsw]);
        #pragma unroll
        for (int mi = 0; mi < 4; mi++)
          acc[mi][ni] = __builtin_amdgcn_mfma_f32_16x16x32_bf16(
              af[mi], bf, acc[mi][ni], 0, 0, 0);
      }
    }
  };

  if (PRECONV) {
    // ---- prologue: tiles 0,1 in flight; wait tile 0 only ----
    stage(0, &As[0][0], &Bs[0][0]);
    stage(1, &As[1][0], &Bs[1][0]);
    asm volatile("s_waitcnt vmcnt(9)" ::: "memory");
    __builtin_amdgcn_s_barrier();

    #pragma unroll 1
    for (int t = 0; t < NSTAGE; t += 2) {
      // tile t (buf0); tile t+1's 9 loads in flight
      __builtin_amdgcn_s_setprio(1);
      compute(&As[0][0], &Bs[0][0]);
      __builtin_amdgcn_s_setprio(0);
      __builtin_amdgcn_s_barrier();          // all waves done reading buf0
      if (t + 2 < NSTAGE) {
        stage(t + 2, &As[0][0], &Bs[0][0]);  // 18 outstanding
        asm volatile("s_waitcnt vmcnt(9)" ::: "memory");  // tile t+1 ready
      } else {
        asm volatile("s_waitcnt vmcnt(0)" ::: "memory");  // last tile ready
      }
      __builtin_amdgcn_s_barrier();          // tile t+1 visible to all waves

      // tile t+1 (buf1); tile t+2's 9 loads in flight
      __builtin_amdgcn_s_setprio(1);
      compute(&As[1][0], &Bs[1][0]);
      __builtin_amdgcn_s_setprio(0);
      __builtin_amdgcn_s_barrier();          // all waves done reading buf1
      if (t + 3 < NSTAGE) {
        stage(t + 3, &As[1][0], &Bs[1][0]);
        asm volatile("s_waitcnt vmcnt(9)" ::: "memory");  // tile t+2 ready
      }
      __builtin_amdgcn_s_barrier();
    }
  } else {
    // ---- fallback (F fp32 direct): simple single-buffer drain loop ----
    for (int ks = 0; ks < NSTAGE; ks++) {
      const int k0 = ks * BKS;
      #pragma unroll
      for (int t = 0; t < 8; t++) {
        const int s2   = (wave << 3) + t;
        const int col  = ((s2 & 31) << 4) + rr;
        const int half = s2 >> 5;
        async_copy16(Wb + (size_t)col * ND + k0 + half * 32 + koff,
                     &Bs[0][s2 * 512]);
      }
      #pragma unroll
      for (int i = 0; i < 2; i++) {
        const int j   = tid * 2 + i;
        const int row = j >> 4;
        const int kq  = j & 15;
        const float4 v = *reinterpret_cast<const float4*>(
            F + (size_t)(m0 + row) * ND + k0 + kq * 4);
        ushort4 s4;
        s4.x = f2bf(v.x); s4.y = f2bf(v.y); s4.z = f2bf(v.z); s4.w = f2bf(v.w);
        const int half = kq >> 3;
        const int u    = ((kq >> 1) & 3) ^ (row & 3);   // swizzled 16-B chunk
        *reinterpret_cast<ushort4*>(
            &As[0][half * 2048 + row * 32 + u * 8 + (kq & 1) * 4]) = s4;
      }
      __syncthreads();
      compute(&As[0][0], &Bs[0][0]);
      __syncthreads();
    }
  }

  // ---- epilogue: fused softmax over C=512 ----
  // C/D layout: col = lane15 (+wave*64+ni*16), row = quad*4 + reg (+mi*16)
  #pragma unroll
  for (int mi = 0; mi < 4; mi++)
    #pragma unroll
    for (int r = 0; r < 4; r++) {
      float m = acc[mi][0][r];
      #pragma unroll
      for (int ni = 1; ni < 4; ni++) m = fmaxf(m, acc[mi][ni][r]);
      #pragma unroll
      for (int off = 1; off < 16; off <<= 1) m = fmaxf(m, __shfl_xor(m, off, 64));
      if (lane15 == 0) redmax[wave][mi * 16 + quad * 4 + r] = m;
    }
  __syncthreads();

  float rsum[4][4];
  #pragma unroll
  for (int mi = 0; mi < 4; mi++)
    #pragma unroll
    for (int r = 0; r < 4; r++) {
      const int row = mi * 16 + quad * 4 + r;
      float m = redmax[0][row];
      #pragma unroll
      for (int w = 1; w < NWAVE; w++) m = fmaxf(m, redmax[w][row]);
      float s = 0.f;
      #pragma unroll
      for (int ni = 0; ni < 4; ni++) {
        const float e = __expf(acc[mi][ni][r] - m);
        acc[mi][ni][r] = e;
        s += e;
      }
      #pragma unroll
      for (int off = 1; off < 16; off <<= 1) s += __shfl_xor(s, off, 64);
      rsum[mi][r] = s;
    }
  if (lane15 == 0) {
    #pragma unroll
    for (int mi = 0; mi < 4; mi++)
      #pragma unroll
      for (int r = 0; r < 4; r++)
        redsum[wave][mi * 16 + quad * 4 + r] = rsum[mi][r];
  }
  __syncthreads();

  #pragma unroll
  for (int mi = 0; mi < 4; mi++)
    #pragma unroll
    for (int r = 0; r < 4; r++) {
      const int row = mi * 16 + quad * 4 + r;
      float s = redsum[0][row];
      #pragma unroll
      for (int w = 1; w < NWAVE; w++) s += redsum[w][row];
      const float inv = 1.f / s;
      const size_t gr = (size_t)(m0 + row) * NC;
      #pragma unroll
      for (int ni = 0; ni < 4; ni++) {
        const int col = wave * 64 + ni * 16 + lane15;
        const float v = acc[mi][ni][r] * inv;
        out_soft[gr + col] = v;
        out_raw [gr + col] = v;
      }
    }
}

// ---------------- fused convert(+pool): F fp32 -> Fb bf16, partial sums over T ----------------
// grid (32 zchunks, 16 b), 512 threads: tid covers (thalf = tid>>8, d-quad = tid&255)
template<bool WRITE_FB>
__global__ __launch_bounds__(512) void convert_pool_kernel(
    const float* __restrict__ F, unsigned short* __restrict__ Fb,
    float* __restrict__ part)    // part[32][16][1024]
{
  __shared__ float4 psum[512];
  const int tid = threadIdx.x;
  const int z = blockIdx.x;
  const int b = blockIdx.y;
  const int th = tid >> 8;              // 0/1
  const int d4 = (tid & 255) * 4;

  float4 s = (float4){0.f, 0.f, 0.f, 0.f};
  const size_t base = ((size_t)b * NT + z * 64) * ND;
  #pragma unroll 4
  for (int t = th; t < 64; t += 2) {
    const size_t idx = base + (size_t)t * ND + d4;
    const float4 v = *reinterpret_cast<const float4*>(F + idx);
    if (WRITE_FB) {
      ushort4 s4;
      s4.x = f2bf(v.x); s4.y = f2bf(v.y); s4.z = f2bf(v.z); s4.w = f2bf(v.w);
      *reinterpret_cast<ushort4*>(Fb + idx) = s4;
    }
    s.x += v.x; s.y += v.y; s.z += v.z; s.w += v.w;
  }
  psum[tid] = s;
  __syncthreads();
  if (tid < 256) {
    const float4 a = psum[tid];
    const float4 c = psum[tid + 256];
    float4 r;
    r.x = a.x + c.x; r.y = a.y + c.y; r.z = a.z + c.z; r.w = a.w + c.w;
    *reinterpret_cast<float4*>(part + (size_t)(z * NB + b) * ND + d4) = r;
  }
}

// ---------------- W fp32 -> bf16 ----------------
__global__ __launch_bounds__(256) void convw_kernel(
    const float* __restrict__ W, unsigned short* __restrict__ Wb)
{
  const size_t j = ((size_t)blockIdx.x * 256 + threadIdx.x) * 8;
  const float4 a = *reinterpret_cast<const float4*>(W + j);
  const float4 c = *reinterpret_cast<const float4*>(W + j + 4);
  ushort4 lo, hi;
  lo.x = f2bf(a.x); lo.y = f2bf(a.y); lo.z = f2bf(a.z); lo.w = f2bf(a.w);
  hi.x = f2bf(c.x); hi.y = f2bf(c.y); hi.z = f2bf(c.z); hi.w = f2bf(c.w);
  *reinterpret_cast<ushort4*>(Wb + j) = lo;
  *reinterpret_cast<ushort4*>(Wb + j + 4) = hi;
}

// ---------------- logits = pooled @ W^T + b (fp32) ----------------
__global__ __launch_bounds__(512) void logits_kernel(
    const float* __restrict__ part, const float* __restrict__ W,
    const float* __restrict__ bias, float* __restrict__ out_logits)
{
  __shared__ float p[ND];
  const int b = blockIdx.x;
  const int tid = threadIdx.x;
  for (int i = tid; i < ND; i += 512) {
    float s = 0.f;
    #pragma unroll
    for (int z = 0; z < 32; z++) s += part[(size_t)(z * NB + b) * ND + i];
    p[i] = s * (1.f / NT);
  }
  __syncthreads();
  const int c = tid;
  const float* wr = W + (size_t)c * ND;
  float s = 0.f;
  for (int k = 0; k < ND; k++) s = fmaf(p[k], wr[k], s);
  out_logits[b * NC + c] = s + bias[c];
}

// ---------------- cross-entropy loss (fp32) ----------------
__global__ __launch_bounds__(512) void loss_kernel(
    const float* __restrict__ logits, const int* __restrict__ labels,
    float* __restrict__ out_loss)
{
  __shared__ float red[8];
  const int tid = threadIdx.x;
  float acc = 0.f;
  for (int b = 0; b < NB; b++) {
    const float v = logits[b * NC + tid];
    float m = v;
    #pragma unroll
    for (int off = 32; off; off >>= 1) m = fmaxf(m, __shfl_xor(m, off, 64));
    if ((tid & 63) == 0) red[tid >> 6] = m;
    __syncthreads();
    m = red[0];
    #pragma unroll
    for (int w = 1; w < 8; w++) m = fmaxf(m, red[w]);
    __syncthreads();
    float e = expf(v - m);
    #pragma unroll
    for (int off = 32; off; off >>= 1) e += __shfl_xor(e, off, 64);
    if ((tid & 63) == 0) red[tid >> 6] = e;
    __syncthreads();
    if (tid == 0) {
      float s = red[0] + red[1] + red[2] + red[3] + red[4] + red[5] + red[6] + red[7];
      const int lab = labels[b];
      acc += -(logits[b * NC + lab] - m - logf(s));
    }
    __syncthreads();
  }
  if (tid == 0) out_loss[0] = acc * (1.f / NB);
}

extern "C" void kernel_launch(void* const* d_in, const int* in_sizes, int n_in,
                              void* d_out, int out_size, void* d_ws, size_t ws_size,
                              hipStream_t stream) {
  const float* F      = (const float*)d_in[0];   // [16,2048,1024]
  const int*   labels = (const int*)  d_in[1];   // [16]
  const float* W      = (const float*)d_in[2];   // [512,1024]
  const float* bias   = (const float*)d_in[3];   // [512]

  float* out        = (float*)d_out;
  float* out_soft   = out;
  float* out_raw    = out + (size_t)NM * NC;
  float* out_logits = out + (size_t)2 * NM * NC;
  float* out_loss   = out_logits + (size_t)NB * NC;

  // ws layout: part [0, 2 MiB) | Wb [2 MiB, 3 MiB) | Fb [4 MiB, 68 MiB)
  char* ws = (char*)d_ws;
  float* part = (float*)ws;                                     // 32*16*1024 f32
  unsigned short* Wb = (unsigned short*)(ws + (2u << 20));      // 512*1024 bf16
  unsigned short* Fb = (unsigned short*)(ws + (4u << 20));      // 32768*1024 bf16
  const bool preconv = ws_size >= (4u << 20) + (size_t)NM * ND * 2;

  if (preconv) {
    convert_pool_kernel<true><<<dim3(32, NB), 512, 0, stream>>>(F, Fb, part);
    convw_kernel<<<NC * ND / (256 * 8), 256, 0, stream>>>(W, Wb);
    cam_softmax_kernel<true><<<NM / BM, 512, 0, stream>>>(Fb, F, Wb, out_soft, out_raw);
  } else {
    convert_pool_kernel<false><<<dim3(32, NB), 512, 0, stream>>>(F, Fb, part);
    convw_kernel<<<NC * ND / (256 * 8), 256, 0, stream>>>(W, Wb);
    cam_softmax_kernel<false><<<NM / BM, 512, 0, stream>>>(Fb, F, Wb, out_soft, out_raw);
  }
  logits_kernel<<<NB, 512, 0, stream>>>(part, W, bias, out_logits);
  loss_kernel<<<1, 512, 0, stream>>>(out_logits, labels, out_loss);
}